// Round 4
// baseline (873.760 us; speedup 1.0000x reference)
//
#include <hip/hip_runtime.h>
#include <stdint.h>

#define D 128
#define SCAN_TILE 1024  // elements per scan block (256 thr x 4)

typedef __attribute__((ext_vector_type(8))) short bf16x8_t;
typedef __attribute__((ext_vector_type(4))) float f32x4_t;

__device__ inline unsigned short f2bf(float x) {
    unsigned int u = __float_as_uint(x);
    unsigned int r = (u + 0x7fffu + ((u >> 16) & 1u)) >> 16;   // RNE
    return (unsigned short)r;
}
__device__ inline float bflo(unsigned v) { return __uint_as_float(v << 16); }
__device__ inline float bfhi(unsigned v) { return __uint_as_float(v & 0xffff0000u); }

// ---------------------------------------------------------------------------
// f32 -> bf16 bulk convert (8 elems/thread/iter, 16B stores)
// ---------------------------------------------------------------------------
__global__ __launch_bounds__(256) void f32_to_bf16_kernel(
        const float* __restrict__ in, unsigned short* __restrict__ out, int n8) {
    int stride = gridDim.x * blockDim.x;
    for (int i = blockIdx.x * blockDim.x + threadIdx.x; i < n8; i += stride) {
        float4 v0 = *(const float4*)(in + (size_t)i * 8);
        float4 v1 = *(const float4*)(in + (size_t)i * 8 + 4);
        uint4 o;
        o.x = f2bf(v0.x) | ((unsigned)f2bf(v0.y) << 16);
        o.y = f2bf(v0.z) | ((unsigned)f2bf(v0.w) << 16);
        o.z = f2bf(v1.x) | ((unsigned)f2bf(v1.y) << 16);
        o.w = f2bf(v1.z) | ((unsigned)f2bf(v1.w) << 16);
        *(uint4*)(out + (size_t)i * 8) = o;
    }
}

// ---------------------------------------------------------------------------
// deg histogram
// ---------------------------------------------------------------------------
__global__ void count_deg_kernel(const int* __restrict__ ea, const int* __restrict__ ep,
                                 int E, int* __restrict__ degA, int* __restrict__ degP) {
    int stride = gridDim.x * blockDim.x;
    for (int e = blockIdx.x * blockDim.x + threadIdx.x; e < E; e += stride) {
        atomicAdd(&degA[ea[e]], 1);
        atomicAdd(&degP[ep[e]], 1);
    }
}

// ---------------------------------------------------------------------------
// 3-pass device-wide exclusive scan over BOTH deg arrays
// ---------------------------------------------------------------------------
__global__ __launch_bounds__(256) void scan_partials_kernel(
        const int* __restrict__ degA, int nA,
        const int* __restrict__ degP, int nP, int gA,
        int* __restrict__ partials) {
    const int* deg; int n;
    int b = blockIdx.x;
    if (b < gA) { deg = degA; n = nA; }
    else        { deg = degP; n = nP; b -= gA; }
    int tid = threadIdx.x;
    int i0 = b * SCAN_TILE + tid * 4;
    int s = 0;
    if (i0 + 3 < n) {
        int4 d = *(const int4*)(deg + i0);
        s = d.x + d.y + d.z + d.w;
    } else {
        for (int j = 0; j < 4; ++j) if (i0 + j < n) s += deg[i0 + j];
    }
#pragma unroll
    for (int off = 32; off; off >>= 1) s += __shfl_xor(s, off);
    __shared__ int wsum[4];
    if ((tid & 63) == 0) wsum[tid >> 6] = s;
    __syncthreads();
    if (tid == 0) partials[blockIdx.x] = wsum[0] + wsum[1] + wsum[2] + wsum[3];
}

__global__ __launch_bounds__(1024) void scan_block_sums_kernel(
        int* __restrict__ partials, int gA, int gP,
        int* __restrict__ rsA_end, int* __restrict__ rsP_end) {
    __shared__ int s[1024];
    int n = gA + gP;
    int tid = threadIdx.x;
    int v = (tid < n) ? partials[tid] : 0;
    s[tid] = v;
    __syncthreads();
    for (int off = 1; off < 1024; off <<= 1) {
        int add = 0;
        if (tid >= off && ((tid < gA) || (tid - off >= gA))) add = s[tid - off];
        __syncthreads();
        s[tid] += add;
        __syncthreads();
    }
    if (tid == gA - 1)  *rsA_end = s[tid];
    if (tid == n - 1)   *rsP_end = s[tid];
    if (tid < n) partials[tid] = s[tid] - v;
}

__global__ __launch_bounds__(256) void scan_write_kernel(
        const int* __restrict__ degA, int nA, int* __restrict__ rsA, int* __restrict__ curA,
        const int* __restrict__ degP, int nP, int* __restrict__ rsP, int* __restrict__ curP,
        int gA, const int* __restrict__ partials) {
    const int* deg; int n; int* rs; int* cur;
    int b = blockIdx.x;
    int part = partials[blockIdx.x];
    if (b < gA) { deg = degA; n = nA; rs = rsA; cur = curA; }
    else        { deg = degP; n = nP; rs = rsP; cur = curP; b -= gA; }
    int tid = threadIdx.x;
    int lane = tid & 63, wid = tid >> 6;
    int i0 = b * SCAN_TILE + tid * 4;

    int4 d = make_int4(0, 0, 0, 0);
    if (i0 + 3 < n) {
        d = *(const int4*)(deg + i0);
    } else {
        if (i0 + 0 < n) d.x = deg[i0 + 0];
        if (i0 + 1 < n) d.y = deg[i0 + 1];
        if (i0 + 2 < n) d.z = deg[i0 + 2];
        if (i0 + 3 < n) d.w = deg[i0 + 3];
    }
    int tsum = d.x + d.y + d.z + d.w;

    int x = tsum;
#pragma unroll
    for (int off = 1; off < 64; off <<= 1) {
        int y = __shfl_up(x, off);
        if (lane >= off) x += y;
    }
    int excl = x - tsum;

    __shared__ int wsum[4];
    if (lane == 63) wsum[wid] = x;
    __syncthreads();
    int woff = 0;
#pragma unroll
    for (int w = 0; w < 4; ++w) if (w < wid) woff += wsum[w];

    int off0 = part + woff + excl;
    int4 o;
    o.x = off0;
    o.y = off0 + d.x;
    o.z = o.y + d.y;
    o.w = o.z + d.z;
    if (i0 + 3 < n) {
        *(int4*)(rs + i0) = o;
        *(int4*)(cur + i0) = o;
    } else {
        if (i0 + 0 < n) { rs[i0 + 0] = o.x; cur[i0 + 0] = o.x; }
        if (i0 + 1 < n) { rs[i0 + 1] = o.y; cur[i0 + 1] = o.y; }
        if (i0 + 2 < n) { rs[i0 + 2] = o.z; cur[i0 + 2] = o.z; }
        if (i0 + 3 < n) { rs[i0 + 3] = o.w; cur[i0 + 3] = o.w; }
    }
}

// ---------------------------------------------------------------------------
// CSR fill via atomic cursors
// ---------------------------------------------------------------------------
__global__ void csr_fill_kernel(const int* __restrict__ ea, const int* __restrict__ ep, int E,
                                int* __restrict__ curA, int* __restrict__ curP,
                                int* __restrict__ csrA, int* __restrict__ csrP) {
    int stride = gridDim.x * blockDim.x;
    for (int e = blockIdx.x * blockDim.x + threadIdx.x; e < E; e += stride) {
        int a = ea[e], p = ep[e];
        int sa = atomicAdd(&curA[a], 1);
        csrA[sa] = p;
        int sp = atomicAdd(&curP[p], 1);
        csrP[sp] = a;
    }
}

// ---------------------------------------------------------------------------
// W pre-pack (unchanged): Bcat=[Ws;Wm] -> bf16 MFMA fragment order
// ---------------------------------------------------------------------------
__global__ __launch_bounds__(256) void pack_w_kernel(
        const float* __restrict__ WsA, const float* __restrict__ WsP,
        const float* __restrict__ Wa2p, const float* __restrict__ Wp2a,
        unsigned short* __restrict__ Bpack) {
    int combo = blockIdx.x >> 4;
    int e = (blockIdx.x & 15) * 256 + threadIdx.x;   // 0..4095
    int layer = combo >> 1;
    const float* Ws = ((combo & 1) ? WsP : WsA) + (size_t)layer * D * D;
    const float* Wm = ((combo & 1) ? Wa2p : Wp2a) + (size_t)layer * D * D;

    int f = e >> 6, lane = e & 63;
    int nf = f >> 3, ks = f & 7;
    int k0 = ks * 32 + (lane >> 4) * 8;
    int col = nf * 16 + (lane & 15);

    unsigned short v[8];
#pragma unroll
    for (int j = 0; j < 8; ++j) {
        int k = k0 + j;
        float x = (k < D) ? Ws[(size_t)k * D + col] : Wm[(size_t)(k - D) * D + col];
        v[j] = f2bf(x);
    }
    uint4 o;
    o.x = v[0] | ((unsigned)v[1] << 16);
    o.y = v[2] | ((unsigned)v[3] << 16);
    o.z = v[4] | ((unsigned)v[5] << 16);
    o.w = v[6] | ((unsigned)v[7] << 16);
    *(uint4*)(Bpack + (size_t)combo * 32768 + (size_t)e * 8) = o;
}

// ---------------------------------------------------------------------------
// Fused gather + MFMA node update (all-bf16 data path):
//   out = maybe_relu( [xs | sum_{s in N(r)} xg[s]] @ Bpack + bs + deg*bm )
// Block = 64 rows x 128 cols, 4 waves. LDS tile [64][256] bf16 (32KB),
// XOR-swizzled byte^=(row&7)<<4 against the 512B-stride bank conflict.
// Wave w gathers rows w*16..w*16+15 (2 cols/lane, 256B/row coalesced),
// accumulates f32, writes bf16 into the K=[128,256) half of the tile.
// ---------------------------------------------------------------------------
__global__ __launch_bounds__(256) void fused_gather_linear_mfma(
        const unsigned short* __restrict__ xs,    // [n][128] bf16 self feats
        const unsigned short* __restrict__ xg,    // [nsrc][128] bf16 gather table
        const int* __restrict__ rs, const int* __restrict__ csr,
        const unsigned short* __restrict__ Bpack,
        const float* __restrict__ bs, const float* __restrict__ bm,
        const int* __restrict__ deg, int relu, int n,
        unsigned short* __restrict__ out) {
    __shared__ uint4 lds4[2048];   // 32 KB
    unsigned char* lds = (unsigned char*)lds4;
    int tid = threadIdx.x;
    int wave = tid >> 6, lane = tid & 63;
    int r_base = blockIdx.x * 64;

    // ---- stage xs half (K 0..127): 1024 16B chunks, 4 per thread ----
#pragma unroll
    for (int i = 0; i < 4; ++i) {
        int c = i * 256 + tid;        // 0..1023
        int row = c >> 4;             // 0..63
        int kb = (c & 15) * 16;       // byte offset within 256B xs row part
        int rg = r_base + row;
        uint4 w = make_uint4(0, 0, 0, 0);
        if (rg < n)
            w = *(const uint4*)((const unsigned char*)xs + (size_t)rg * 256 + kb);
        unsigned addr = ((unsigned)(row * 512 + kb)) ^ ((unsigned)((row & 7) << 4));
        *(uint4*)(lds + addr) = w;
    }

    // ---- gather+sum into xm half (K 128..255) ----
    for (int rr = 0; rr < 16; ++rr) {
        int row = wave * 16 + rr;
        int rg = r_base + row;
        float ax = 0.f, ay = 0.f;
        if (rg < n) {
            int s0 = rs[rg], s1 = rs[rg + 1];
            for (int j = s0; j < s1; ++j) {
                int s = csr[j];
                unsigned v = *(const unsigned*)((const unsigned char*)xg
                                                + (size_t)s * 256 + lane * 4);
                ax += bflo(v);
                ay += bfhi(v);
            }
        }
        unsigned o = f2bf(ax) | ((unsigned)f2bf(ay) << 16);
        unsigned addr = ((unsigned)(row * 512 + 256 + lane * 4))
                        ^ ((unsigned)((row & 7) << 4));
        *(unsigned*)(lds + addr) = o;
    }
    __syncthreads();

    // ---- A fragments: a[ks][j] = tile[lrow][ks*32 + (lane>>4)*8 + j] ----
    int lrow = wave * 16 + (lane & 15);
    bf16x8_t a[8];
#pragma unroll
    for (int ks = 0; ks < 8; ++ks) {
        unsigned addr = ((unsigned)(lrow * 512 + ks * 64 + (lane >> 4) * 16))
                        ^ ((unsigned)((lrow & 7) << 4));
        a[ks] = *(const bf16x8_t*)(lds + addr);
    }

    // ---- MFMA main loop ----
    f32x4_t acc[8];
#pragma unroll
    for (int nf = 0; nf < 8; ++nf) acc[nf] = (f32x4_t){0.f, 0.f, 0.f, 0.f};

    const bf16x8_t* bp = (const bf16x8_t*)Bpack;
#pragma unroll
    for (int nf = 0; nf < 8; ++nf) {
#pragma unroll
        for (int ks = 0; ks < 8; ++ks) {
            bf16x8_t b = bp[(nf * 8 + ks) * 64 + lane];
            acc[nf] = __builtin_amdgcn_mfma_f32_16x16x32_bf16(a[ks], b, acc[nf], 0, 0, 0);
        }
    }

    // ---- epilogue: + bs + deg*bm, relu, bf16 store ----
    int rb2 = r_base + wave * 16 + (lane >> 4) * 4;
    float dg[4];
#pragma unroll
    for (int rr = 0; rr < 4; ++rr)
        dg[rr] = (rb2 + rr < n) ? (float)deg[rb2 + rr] : 0.f;

#pragma unroll
    for (int nf = 0; nf < 8; ++nf) {
        int col = nf * 16 + (lane & 15);
        float bsv = bs[col], bmv = bm[col];
#pragma unroll
        for (int rr = 0; rr < 4; ++rr) {
            int r = rb2 + rr;
            if (r < n) {
                float v = acc[nf][rr] + bsv + dg[rr] * bmv;
                if (relu) v = fmaxf(v, 0.f);
                out[(size_t)r * D + col] = f2bf(v);
            }
        }
    }
}

// ---------------------------------------------------------------------------
// supervision dot products on bf16 embeddings: one wave per pair
// ---------------------------------------------------------------------------
__global__ __launch_bounds__(256) void dot_kernel(
        const unsigned short* __restrict__ za, const unsigned short* __restrict__ zp,
        const int* __restrict__ sa, const int* __restrict__ sp, int S,
        float* __restrict__ out) {
    int gw   = (blockIdx.x * 256 + threadIdx.x) >> 6;
    int lane = threadIdx.x & 63;
    int nw   = (gridDim.x * 256) >> 6;
    for (int i = gw; i < S; i += nw) {
        int a = sa[i], p = sp[i];
        unsigned ua = *(const unsigned*)(za + (size_t)a * D + lane * 2);
        unsigned up = *(const unsigned*)(zp + (size_t)p * D + lane * 2);
        float s = bflo(ua) * bflo(up) + bfhi(ua) * bfhi(up);
#pragma unroll
        for (int off = 32; off > 0; off >>= 1) s += __shfl_xor(s, off);
        if (lane == 0) out[i] = s;
    }
}

// ---------------------------------------------------------------------------
extern "C" void kernel_launch(void* const* d_in, const int* in_sizes, int n_in,
                              void* d_out, int out_size, void* d_ws, size_t ws_size,
                              hipStream_t stream) {
    const float* x_a  = (const float*)d_in[0];
    const float* x_p  = (const float*)d_in[1];
    const int*   ea   = (const int*)d_in[2];
    const int*   ep   = (const int*)d_in[3];
    const int*   sa   = (const int*)d_in[4];
    const int*   sp   = (const int*)d_in[5];
    const float* WsA  = (const float*)d_in[6];
    const float* bsA  = (const float*)d_in[7];
    const float* WsP  = (const float*)d_in[8];
    const float* bsP  = (const float*)d_in[9];
    const float* Wa2p = (const float*)d_in[10];
    const float* ba2p = (const float*)d_in[11];
    const float* Wp2a = (const float*)d_in[12];
    const float* bp2a = (const float*)d_in[13];

    const int nA = in_sizes[0] / D;   // 100000
    const int nP = in_sizes[1] / D;   // 200000
    const int E  = in_sizes[2];       // 600000
    const int S  = in_sizes[4];       // 100000

    // ---- workspace layout (~245 MB) ----
    char* ws = (char*)d_ws;
    size_t curoff = 0;
    auto alloc = [&](size_t bytes) -> void* {
        void* p = ws + curoff;
        curoff = (curoff + bytes + 255) & ~(size_t)255;
        return p;
    };
    unsigned short* xb_a = (unsigned short*)alloc((size_t)nA * D * 2);
    unsigned short* xb_p = (unsigned short*)alloc((size_t)nP * D * 2);
    unsigned short* y_a  = (unsigned short*)alloc((size_t)nA * D * 2);
    unsigned short* y_p  = (unsigned short*)alloc((size_t)nP * D * 2);
    unsigned short* z_a  = (unsigned short*)alloc((size_t)nA * D * 2);
    unsigned short* z_p  = (unsigned short*)alloc((size_t)nP * D * 2);
    int* degA = (int*)alloc((size_t)nA * 4);
    int* degP = (int*)alloc((size_t)nP * 4);
    int* rsA  = (int*)alloc(((size_t)nA + 1) * 4);
    int* rsP  = (int*)alloc(((size_t)nP + 1) * 4);
    int* curA = (int*)alloc((size_t)nA * 4);
    int* curP = (int*)alloc((size_t)nP * 4);
    int* csrA = (int*)alloc((size_t)E * 4);
    int* csrP = (int*)alloc((size_t)E * 4);
    const int gA = (nA + SCAN_TILE - 1) / SCAN_TILE;
    const int gP = (nP + SCAN_TILE - 1) / SCAN_TILE;
    int* partials = (int*)alloc((size_t)(gA + gP) * 4);
    unsigned short* Bpack = (unsigned short*)alloc((size_t)4 * 32768 * 2);  // 256 KB

    // ---- bf16 input copies + graph preprocessing + W packing ----
    f32_to_bf16_kernel<<<1024, 256, 0, stream>>>(x_a, xb_a, nA * D / 8);
    f32_to_bf16_kernel<<<2048, 256, 0, stream>>>(x_p, xb_p, nP * D / 8);
    size_t deg_bytes = (size_t)((char*)degP - (char*)degA) + (size_t)nP * 4;
    hipMemsetAsync(degA, 0, deg_bytes, stream);
    pack_w_kernel<<<64, 256, 0, stream>>>(WsA, WsP, Wa2p, Wp2a, Bpack);
    count_deg_kernel<<<1024, 256, 0, stream>>>(ea, ep, E, degA, degP);
    scan_partials_kernel<<<gA + gP, 256, 0, stream>>>(degA, nA, degP, nP, gA, partials);
    scan_block_sums_kernel<<<1, 1024, 0, stream>>>(partials, gA, gP, rsA + nA, rsP + nP);
    scan_write_kernel<<<gA + gP, 256, 0, stream>>>(degA, nA, rsA, curA,
                                                   degP, nP, rsP, curP, gA, partials);
    csr_fill_kernel<<<1024, 256, 0, stream>>>(ea, ep, E, curA, curP, csrA, csrP);

    const int gmA = (nA + 63) / 64;   // 1563
    const int gmP = (nP + 63) / 64;   // 3125

    // ---- layer 0 (relu) ----
    fused_gather_linear_mfma<<<gmA, 256, 0, stream>>>(
        xb_a, xb_p, rsA, csrA, Bpack + 0 * 32768, bsA, bp2a, degA, 1, nA, y_a);
    fused_gather_linear_mfma<<<gmP, 256, 0, stream>>>(
        xb_p, xb_a, rsP, csrP, Bpack + 1 * 32768, bsP, ba2p, degP, 1, nP, y_p);

    // ---- layer 1 (no relu) ----
    fused_gather_linear_mfma<<<gmA, 256, 0, stream>>>(
        y_a, y_p, rsA, csrA, Bpack + 2 * 32768, bsA + D, bp2a + D, degA, 0, nA, z_a);
    fused_gather_linear_mfma<<<gmP, 256, 0, stream>>>(
        y_p, y_a, rsP, csrP, Bpack + 3 * 32768, bsP + D, ba2p + D, degP, 0, nP, z_p);

    // ---- supervision scores ----
    dot_kernel<<<(S + 3) / 4, 256, 0, stream>>>(z_a, z_p, sa, sp, S, (float*)d_out);
}

// Round 5
// 608.517 us; speedup vs baseline: 1.4359x; 1.4359x over previous
//
#include <hip/hip_runtime.h>
#include <stdint.h>

#define D 128
#define SCAN_TILE 1024  // elements per scan block (256 thr x 4)

typedef __attribute__((ext_vector_type(8))) short bf16x8_t;
typedef __attribute__((ext_vector_type(4))) float f32x4_t;

__device__ inline unsigned short f2bf(float x) {
    unsigned int u = __float_as_uint(x);
    unsigned int r = (u + 0x7fffu + ((u >> 16) & 1u)) >> 16;   // RNE
    return (unsigned short)r;
}
__device__ inline float bflo(unsigned v) { return __uint_as_float(v << 16); }
__device__ inline float bfhi(unsigned v) { return __uint_as_float(v & 0xffff0000u); }

// ---------------------------------------------------------------------------
// f32 -> bf16 bulk convert (8 elems/thread/iter, 16B stores)
// ---------------------------------------------------------------------------
__global__ __launch_bounds__(256) void f32_to_bf16_kernel(
        const float* __restrict__ in, unsigned short* __restrict__ out, int n8) {
    int stride = gridDim.x * blockDim.x;
    for (int i = blockIdx.x * blockDim.x + threadIdx.x; i < n8; i += stride) {
        float4 v0 = *(const float4*)(in + (size_t)i * 8);
        float4 v1 = *(const float4*)(in + (size_t)i * 8 + 4);
        uint4 o;
        o.x = f2bf(v0.x) | ((unsigned)f2bf(v0.y) << 16);
        o.y = f2bf(v0.z) | ((unsigned)f2bf(v0.w) << 16);
        o.z = f2bf(v1.x) | ((unsigned)f2bf(v1.y) << 16);
        o.w = f2bf(v1.z) | ((unsigned)f2bf(v1.w) << 16);
        *(uint4*)(out + (size_t)i * 8) = o;
    }
}

// ---------------------------------------------------------------------------
// deg histogram
// ---------------------------------------------------------------------------
__global__ void count_deg_kernel(const int* __restrict__ ea, const int* __restrict__ ep,
                                 int E, int* __restrict__ degA, int* __restrict__ degP) {
    int stride = gridDim.x * blockDim.x;
    for (int e = blockIdx.x * blockDim.x + threadIdx.x; e < E; e += stride) {
        atomicAdd(&degA[ea[e]], 1);
        atomicAdd(&degP[ep[e]], 1);
    }
}

// ---------------------------------------------------------------------------
// 3-pass device-wide exclusive scan over BOTH deg arrays
// ---------------------------------------------------------------------------
__global__ __launch_bounds__(256) void scan_partials_kernel(
        const int* __restrict__ degA, int nA,
        const int* __restrict__ degP, int nP, int gA,
        int* __restrict__ partials) {
    const int* deg; int n;
    int b = blockIdx.x;
    if (b < gA) { deg = degA; n = nA; }
    else        { deg = degP; n = nP; b -= gA; }
    int tid = threadIdx.x;
    int i0 = b * SCAN_TILE + tid * 4;
    int s = 0;
    if (i0 + 3 < n) {
        int4 d = *(const int4*)(deg + i0);
        s = d.x + d.y + d.z + d.w;
    } else {
        for (int j = 0; j < 4; ++j) if (i0 + j < n) s += deg[i0 + j];
    }
#pragma unroll
    for (int off = 32; off; off >>= 1) s += __shfl_xor(s, off);
    __shared__ int wsum[4];
    if ((tid & 63) == 0) wsum[tid >> 6] = s;
    __syncthreads();
    if (tid == 0) partials[blockIdx.x] = wsum[0] + wsum[1] + wsum[2] + wsum[3];
}

__global__ __launch_bounds__(1024) void scan_block_sums_kernel(
        int* __restrict__ partials, int gA, int gP,
        int* __restrict__ rsA_end, int* __restrict__ rsP_end) {
    __shared__ int s[1024];
    int n = gA + gP;
    int tid = threadIdx.x;
    int v = (tid < n) ? partials[tid] : 0;
    s[tid] = v;
    __syncthreads();
    for (int off = 1; off < 1024; off <<= 1) {
        int add = 0;
        if (tid >= off && ((tid < gA) || (tid - off >= gA))) add = s[tid - off];
        __syncthreads();
        s[tid] += add;
        __syncthreads();
    }
    if (tid == gA - 1)  *rsA_end = s[tid];
    if (tid == n - 1)   *rsP_end = s[tid];
    if (tid < n) partials[tid] = s[tid] - v;
}

__global__ __launch_bounds__(256) void scan_write_kernel(
        const int* __restrict__ degA, int nA, int* __restrict__ rsA, int* __restrict__ curA,
        const int* __restrict__ degP, int nP, int* __restrict__ rsP, int* __restrict__ curP,
        int gA, const int* __restrict__ partials) {
    const int* deg; int n; int* rs; int* cur;
    int b = blockIdx.x;
    int part = partials[blockIdx.x];
    if (b < gA) { deg = degA; n = nA; rs = rsA; cur = curA; }
    else        { deg = degP; n = nP; rs = rsP; cur = curP; b -= gA; }
    int tid = threadIdx.x;
    int lane = tid & 63, wid = tid >> 6;
    int i0 = b * SCAN_TILE + tid * 4;

    int4 d = make_int4(0, 0, 0, 0);
    if (i0 + 3 < n) {
        d = *(const int4*)(deg + i0);
    } else {
        if (i0 + 0 < n) d.x = deg[i0 + 0];
        if (i0 + 1 < n) d.y = deg[i0 + 1];
        if (i0 + 2 < n) d.z = deg[i0 + 2];
        if (i0 + 3 < n) d.w = deg[i0 + 3];
    }
    int tsum = d.x + d.y + d.z + d.w;

    int x = tsum;
#pragma unroll
    for (int off = 1; off < 64; off <<= 1) {
        int y = __shfl_up(x, off);
        if (lane >= off) x += y;
    }
    int excl = x - tsum;

    __shared__ int wsum[4];
    if (lane == 63) wsum[wid] = x;
    __syncthreads();
    int woff = 0;
#pragma unroll
    for (int w = 0; w < 4; ++w) if (w < wid) woff += wsum[w];

    int off0 = part + woff + excl;
    int4 o;
    o.x = off0;
    o.y = off0 + d.x;
    o.z = o.y + d.y;
    o.w = o.z + d.z;
    if (i0 + 3 < n) {
        *(int4*)(rs + i0) = o;
        *(int4*)(cur + i0) = o;
    } else {
        if (i0 + 0 < n) { rs[i0 + 0] = o.x; cur[i0 + 0] = o.x; }
        if (i0 + 1 < n) { rs[i0 + 1] = o.y; cur[i0 + 1] = o.y; }
        if (i0 + 2 < n) { rs[i0 + 2] = o.z; cur[i0 + 2] = o.z; }
        if (i0 + 3 < n) { rs[i0 + 3] = o.w; cur[i0 + 3] = o.w; }
    }
}

// ---------------------------------------------------------------------------
// CSR fill via atomic cursors
// ---------------------------------------------------------------------------
__global__ void csr_fill_kernel(const int* __restrict__ ea, const int* __restrict__ ep, int E,
                                int* __restrict__ curA, int* __restrict__ curP,
                                int* __restrict__ csrA, int* __restrict__ csrP) {
    int stride = gridDim.x * blockDim.x;
    for (int e = blockIdx.x * blockDim.x + threadIdx.x; e < E; e += stride) {
        int a = ea[e], p = ep[e];
        int sa = atomicAdd(&curA[a], 1);
        csrA[sa] = p;
        int sp = atomicAdd(&curP[p], 1);
        csrP[sp] = a;
    }
}

// ---------------------------------------------------------------------------
// W pre-pack (unchanged): Bcat=[Ws;Wm] -> bf16 MFMA fragment order
// ---------------------------------------------------------------------------
__global__ __launch_bounds__(256) void pack_w_kernel(
        const float* __restrict__ WsA, const float* __restrict__ WsP,
        const float* __restrict__ Wa2p, const float* __restrict__ Wp2a,
        unsigned short* __restrict__ Bpack) {
    int combo = blockIdx.x >> 4;
    int e = (blockIdx.x & 15) * 256 + threadIdx.x;   // 0..4095
    int layer = combo >> 1;
    const float* Ws = ((combo & 1) ? WsP : WsA) + (size_t)layer * D * D;
    const float* Wm = ((combo & 1) ? Wa2p : Wp2a) + (size_t)layer * D * D;

    int f = e >> 6, lane = e & 63;
    int nf = f >> 3, ks = f & 7;
    int k0 = ks * 32 + (lane >> 4) * 8;
    int col = nf * 16 + (lane & 15);

    unsigned short v[8];
#pragma unroll
    for (int j = 0; j < 8; ++j) {
        int k = k0 + j;
        float x = (k < D) ? Ws[(size_t)k * D + col] : Wm[(size_t)(k - D) * D + col];
        v[j] = f2bf(x);
    }
    uint4 o;
    o.x = v[0] | ((unsigned)v[1] << 16);
    o.y = v[2] | ((unsigned)v[3] << 16);
    o.z = v[4] | ((unsigned)v[5] << 16);
    o.w = v[6] | ((unsigned)v[7] << 16);
    *(uint4*)(Bpack + (size_t)combo * 32768 + (size_t)e * 8) = o;
}

// ---------------------------------------------------------------------------
// bf16 pull-aggregation, latency-optimized:
// one wave per dst row; 4x16-lane subwaves each load 16B/lane (full 256B row),
// neighbors strided across subwaves (4x MLP); combine via shfl_xor(16|32).
// f32 accumulate, bf16 store. No atomics, no zero-init.
// ---------------------------------------------------------------------------
__global__ __launch_bounds__(256) void aggregate_bf16_kernel(
        const unsigned short* __restrict__ xsrc, const int* __restrict__ rs,
        const int* __restrict__ csr, int ndst, unsigned short* __restrict__ agg) {
    int gw   = (blockIdx.x * 256 + threadIdx.x) >> 6;
    int nw   = (gridDim.x * 256) >> 6;
    int lane = threadIdx.x & 63;
    int sub  = lane >> 4;          // 0..3  neighbor stripe
    int sl   = lane & 15;          // 16 lanes x 16B = 256B row
    for (int d = gw; d < ndst; d += nw) {
        int s0 = rs[d], s1 = rs[d + 1];
        float acc[8] = {0.f, 0.f, 0.f, 0.f, 0.f, 0.f, 0.f, 0.f};
        for (int j = s0 + sub; j < s1; j += 4) {
            int s = csr[j];
            uint4 v = *(const uint4*)(xsrc + (size_t)s * D + sl * 8);
            acc[0] += bflo(v.x); acc[1] += bfhi(v.x);
            acc[2] += bflo(v.y); acc[3] += bfhi(v.y);
            acc[4] += bflo(v.z); acc[5] += bfhi(v.z);
            acc[6] += bflo(v.w); acc[7] += bfhi(v.w);
        }
#pragma unroll
        for (int i = 0; i < 8; ++i) {
            acc[i] += __shfl_xor(acc[i], 16);
            acc[i] += __shfl_xor(acc[i], 32);
        }
        if (sub == 0) {
            uint4 o;
            o.x = f2bf(acc[0]) | ((unsigned)f2bf(acc[1]) << 16);
            o.y = f2bf(acc[2]) | ((unsigned)f2bf(acc[3]) << 16);
            o.z = f2bf(acc[4]) | ((unsigned)f2bf(acc[5]) << 16);
            o.w = f2bf(acc[6]) | ((unsigned)f2bf(acc[7]) << 16);
            *(uint4*)(agg + (size_t)d * D + sl * 8) = o;
        }
    }
}

// ---------------------------------------------------------------------------
// MFMA node update (bf16 in/out): out = maybe_relu([xs|xm]@Bpack + bs+deg*bm)
// Block = 64 rows x 128 cols, 4 waves, K=256. LDS tile [64][256] bf16,
// XOR swizzle byte^=(row&7)<<4 kills the 512B-stride bank conflict.
// ---------------------------------------------------------------------------
__global__ __launch_bounds__(256) void linear_mfma_bf16(
        const unsigned short* __restrict__ xs, const unsigned short* __restrict__ xm,
        const unsigned short* __restrict__ Bpack,
        const float* __restrict__ bs, const float* __restrict__ bm,
        const int* __restrict__ deg, int relu, int n,
        unsigned short* __restrict__ out) {
    __shared__ uint4 lds4[2048];   // 32 KB
    unsigned char* lds = (unsigned char*)lds4;
    int tid = threadIdx.x;
    int wave = tid >> 6, lane = tid & 63;
    int r_base = blockIdx.x * 64;

    // ---- stage [xs|xm] tile: 2048 16B chunks, 8 per thread ----
#pragma unroll
    for (int i = 0; i < 8; ++i) {
        int c = i * 256 + tid;        // 0..2047
        int row = c >> 5;             // 0..63
        int kc = (c & 31) * 8;        // bf16 elem offset 0..248
        int rg = r_base + row;
        uint4 w = make_uint4(0, 0, 0, 0);
        if (rg < n) {
            const unsigned short* src = (kc < D) ? (xs + (size_t)rg * D + kc)
                                                 : (xm + (size_t)rg * D + (kc - D));
            w = *(const uint4*)src;
        }
        unsigned addr = ((unsigned)(row * 512 + kc * 2)) ^ ((unsigned)((row & 7) << 4));
        *(uint4*)(lds + addr) = w;
    }
    __syncthreads();

    // ---- A fragments ----
    int lrow = wave * 16 + (lane & 15);
    bf16x8_t a[8];
#pragma unroll
    for (int ks = 0; ks < 8; ++ks) {
        unsigned addr = ((unsigned)(lrow * 512 + ks * 64 + (lane >> 4) * 16))
                        ^ ((unsigned)((lrow & 7) << 4));
        a[ks] = *(const bf16x8_t*)(lds + addr);
    }

    // ---- MFMA main loop ----
    f32x4_t acc[8];
#pragma unroll
    for (int nf = 0; nf < 8; ++nf) acc[nf] = (f32x4_t){0.f, 0.f, 0.f, 0.f};

    const bf16x8_t* bp = (const bf16x8_t*)Bpack;
#pragma unroll
    for (int nf = 0; nf < 8; ++nf) {
#pragma unroll
        for (int ks = 0; ks < 8; ++ks) {
            bf16x8_t b = bp[(nf * 8 + ks) * 64 + lane];
            acc[nf] = __builtin_amdgcn_mfma_f32_16x16x32_bf16(a[ks], b, acc[nf], 0, 0, 0);
        }
    }

    // ---- epilogue: + bs + deg*bm, relu, bf16 store ----
    int rb2 = r_base + wave * 16 + (lane >> 4) * 4;
    float dg[4];
#pragma unroll
    for (int rr = 0; rr < 4; ++rr)
        dg[rr] = (rb2 + rr < n) ? (float)deg[rb2 + rr] : 0.f;

#pragma unroll
    for (int nf = 0; nf < 8; ++nf) {
        int col = nf * 16 + (lane & 15);
        float bsv = bs[col], bmv = bm[col];
#pragma unroll
        for (int rr = 0; rr < 4; ++rr) {
            int r = rb2 + rr;
            if (r < n) {
                float v = acc[nf][rr] + bsv + dg[rr] * bmv;
                if (relu) v = fmaxf(v, 0.f);
                out[(size_t)r * D + col] = f2bf(v);
            }
        }
    }
}

// ---------------------------------------------------------------------------
// supervision dot products on bf16 embeddings: one wave per pair
// ---------------------------------------------------------------------------
__global__ __launch_bounds__(256) void dot_kernel(
        const unsigned short* __restrict__ za, const unsigned short* __restrict__ zp,
        const int* __restrict__ sa, const int* __restrict__ sp, int S,
        float* __restrict__ out) {
    int gw   = (blockIdx.x * 256 + threadIdx.x) >> 6;
    int lane = threadIdx.x & 63;
    int nw   = (gridDim.x * 256) >> 6;
    for (int i = gw; i < S; i += nw) {
        int a = sa[i], p = sp[i];
        unsigned ua = *(const unsigned*)(za + (size_t)a * D + lane * 2);
        unsigned up = *(const unsigned*)(zp + (size_t)p * D + lane * 2);
        float s = bflo(ua) * bflo(up) + bfhi(ua) * bfhi(up);
#pragma unroll
        for (int off = 32; off > 0; off >>= 1) s += __shfl_xor(s, off);
        if (lane == 0) out[i] = s;
    }
}

// ---------------------------------------------------------------------------
extern "C" void kernel_launch(void* const* d_in, const int* in_sizes, int n_in,
                              void* d_out, int out_size, void* d_ws, size_t ws_size,
                              hipStream_t stream) {
    const float* x_a  = (const float*)d_in[0];
    const float* x_p  = (const float*)d_in[1];
    const int*   ea   = (const int*)d_in[2];
    const int*   ep   = (const int*)d_in[3];
    const int*   sa   = (const int*)d_in[4];
    const int*   sp   = (const int*)d_in[5];
    const float* WsA  = (const float*)d_in[6];
    const float* bsA  = (const float*)d_in[7];
    const float* WsP  = (const float*)d_in[8];
    const float* bsP  = (const float*)d_in[9];
    const float* Wa2p = (const float*)d_in[10];
    const float* ba2p = (const float*)d_in[11];
    const float* Wp2a = (const float*)d_in[12];
    const float* bp2a = (const float*)d_in[13];

    const int nA = in_sizes[0] / D;   // 100000
    const int nP = in_sizes[1] / D;   // 200000
    const int E  = in_sizes[2];       // 600000
    const int S  = in_sizes[4];       // 100000

    // ---- workspace layout ----
    char* ws = (char*)d_ws;
    size_t curoff = 0;
    auto alloc = [&](size_t bytes) -> void* {
        void* p = ws + curoff;
        curoff = (curoff + bytes + 255) & ~(size_t)255;
        return p;
    };
    unsigned short* xb_a  = (unsigned short*)alloc((size_t)nA * D * 2);
    unsigned short* xb_p  = (unsigned short*)alloc((size_t)nP * D * 2);
    unsigned short* agg_a = (unsigned short*)alloc((size_t)nA * D * 2);
    unsigned short* agg_p = (unsigned short*)alloc((size_t)nP * D * 2);
    unsigned short* y_a   = (unsigned short*)alloc((size_t)nA * D * 2);
    unsigned short* y_p   = (unsigned short*)alloc((size_t)nP * D * 2);
    unsigned short* z_a   = (unsigned short*)alloc((size_t)nA * D * 2);
    unsigned short* z_p   = (unsigned short*)alloc((size_t)nP * D * 2);
    int* degA = (int*)alloc((size_t)nA * 4);
    int* degP = (int*)alloc((size_t)nP * 4);
    int* rsA  = (int*)alloc(((size_t)nA + 1) * 4);
    int* rsP  = (int*)alloc(((size_t)nP + 1) * 4);
    int* curA = (int*)alloc((size_t)nA * 4);
    int* curP = (int*)alloc((size_t)nP * 4);
    int* csrA = (int*)alloc((size_t)E * 4);
    int* csrP = (int*)alloc((size_t)E * 4);
    const int gA = (nA + SCAN_TILE - 1) / SCAN_TILE;
    const int gP = (nP + SCAN_TILE - 1) / SCAN_TILE;
    int* partials = (int*)alloc((size_t)(gA + gP) * 4);
    unsigned short* Bpack = (unsigned short*)alloc((size_t)4 * 32768 * 2);  // 256 KB

    // ---- bf16 input copies + graph preprocessing + W packing ----
    f32_to_bf16_kernel<<<1024, 256, 0, stream>>>(x_a, xb_a, nA * D / 8);
    f32_to_bf16_kernel<<<2048, 256, 0, stream>>>(x_p, xb_p, nP * D / 8);
    size_t deg_bytes = (size_t)((char*)degP - (char*)degA) + (size_t)nP * 4;
    hipMemsetAsync(degA, 0, deg_bytes, stream);
    pack_w_kernel<<<64, 256, 0, stream>>>(WsA, WsP, Wa2p, Wp2a, Bpack);
    count_deg_kernel<<<1024, 256, 0, stream>>>(ea, ep, E, degA, degP);
    scan_partials_kernel<<<gA + gP, 256, 0, stream>>>(degA, nA, degP, nP, gA, partials);
    scan_block_sums_kernel<<<1, 1024, 0, stream>>>(partials, gA, gP, rsA + nA, rsP + nP);
    scan_write_kernel<<<gA + gP, 256, 0, stream>>>(degA, nA, rsA, curA,
                                                   degP, nP, rsP, curP, gA, partials);
    csr_fill_kernel<<<1024, 256, 0, stream>>>(ea, ep, E, curA, curP, csrA, csrP);

    const int gmA = (nA + 63) / 64;   // 1563
    const int gmP = (nP + 63) / 64;   // 3125

    // ---- layer 0 (relu) ----
    aggregate_bf16_kernel<<<(nA + 3) / 4, 256, 0, stream>>>(xb_p, rsA, csrA, nA, agg_a);
    aggregate_bf16_kernel<<<(nP + 3) / 4, 256, 0, stream>>>(xb_a, rsP, csrP, nP, agg_p);
    linear_mfma_bf16<<<gmA, 256, 0, stream>>>(xb_a, agg_a, Bpack + 0 * 32768,
                                              bsA, bp2a, degA, 1, nA, y_a);
    linear_mfma_bf16<<<gmP, 256, 0, stream>>>(xb_p, agg_p, Bpack + 1 * 32768,
                                              bsP, ba2p, degP, 1, nP, y_p);

    // ---- layer 1 (no relu) ----
    aggregate_bf16_kernel<<<(nA + 3) / 4, 256, 0, stream>>>(y_p, rsA, csrA, nA, agg_a);
    aggregate_bf16_kernel<<<(nP + 3) / 4, 256, 0, stream>>>(y_a, rsP, csrP, nP, agg_p);
    linear_mfma_bf16<<<gmA, 256, 0, stream>>>(y_a, agg_a, Bpack + 2 * 32768,
                                              bsA + D, bp2a + D, degA, 0, nA, z_a);
    linear_mfma_bf16<<<gmP, 256, 0, stream>>>(y_p, agg_p, Bpack + 3 * 32768,
                                              bsP + D, ba2p + D, degP, 0, nP, z_p);

    // ---- supervision scores ----
    dot_kernel<<<(S + 3) / 4, 256, 0, stream>>>(z_a, z_p, sa, sp, S, (float*)d_out);
}